// Round 5
// baseline (529.751 us; speedup 1.0000x reference)
//
#include <hip/hip_runtime.h>
#include <hip/hip_bf16.h>

#define TPB 256
typedef unsigned short us;
typedef __attribute__((ext_vector_type(8))) short bf16x8;
typedef __attribute__((ext_vector_type(4))) float f32x4;

__device__ inline us f2bf(float f){ union{ __hip_bfloat16 h; us s; } x; x.h = __float2bfloat16(f); return x.s; }
__device__ inline float bf2f(us u){ union{unsigned v; float f;} x; x.v = ((unsigned)u)<<16; return x.f; }
__device__ inline void split_pack(const float* v, bf16x8& hi, bf16x8& lo){
  #pragma unroll
  for (int j = 0; j < 8; ++j){
    us h = f2bf(v[j]);
    hi[j] = (short)h;
    lo[j] = (short)f2bf(v[j] - bf2f(h));
  }
}
#define MFMA16(a,b,c) __builtin_amdgcn_mfma_f32_16x16x32_bf16((a),(b),(c),0,0,0)

// ---------------------------------------------------------------- x NCHW f32 -> NHWC f32
__global__ __launch_bounds__(256) void k_transpose_x(const float* __restrict__ x,
                                                     float* __restrict__ xT){
  __shared__ float tile[64][65];
  const int y = blockIdx.x, b = blockIdx.y;
  for (int i = threadIdx.x; i < 4096; i += TPB){
    const int c = i >> 6, xx = i & 63;
    tile[c][xx] = x[b*262144 + c*4096 + y*64 + xx];
  }
  __syncthreads();
  for (int i = threadIdx.x; i < 4096; i += TPB){
    const int xx = i >> 6, c = i & 63;
    xT[(size_t)(b*4096 + y*64 + xx)*64 + c] = tile[c][xx];
  }
}

// ---------------------------------------------------------------- weights -> fragment-linear split-bf16
// per table: [k(9)][plane(2: hi,lo)][kb][n0][lane(64)][j(8)]
// elem = W[co = n0*16+(l&15)][c = kb*32+(l>>4)*8+j][k]
// plane offset within a k: r = (kb*NT + n0)*512 + l*8 + j
__global__ __launch_bounds__(256) void k_prep(
    const float* __restrict__ cw1, const float* __restrict__ ow1, const float* __restrict__ mw1,
    const float* __restrict__ cw2, const float* __restrict__ ow2, const float* __restrict__ mw2,
    us* __restrict__ d1, us* __restrict__ d2, us* __restrict__ a1, us* __restrict__ a2){
  const int e = blockIdx.x*TPB + threadIdx.x;
  { // deform1: CIN=64, NT=8, KB=2, WELEM=8192
    if (e < 147456){
      int k = e/16384, plane = (e%16384)/8192, r = e%8192;
      int kb = r/4096, r2 = r%4096;
      int n0 = r2>>9, q = r2&511, l = q>>3, j = q&7;
      int co = n0*16 + (l&15), c = kb*32 + (l>>4)*8 + j;
      float w = cw1[(co*64 + c)*9 + k];
      us hi = f2bf(w), lo = f2bf(w - bf2f(hi));
      d1[e] = plane ? lo : hi;
    }
  }
  { // deform2: CIN=128, NT=8, KB=4, WELEM=16384
    if (e < 294912){
      int k = e/32768, plane = (e%32768)/16384, r = e%16384;
      int kb = r/4096, r2 = r%4096;
      int n0 = r2>>9, q = r2&511, l = q>>3, j = q&7;
      int co = n0*16 + (l&15), c = kb*32 + (l>>4)*8 + j;
      float w = cw2[(co*128 + c)*9 + k];
      us hi = f2bf(w), lo = f2bf(w - bf2f(hi));
      d2[e] = plane ? lo : hi;
    }
  }
  { // aux1: CIN=64, NT=2, KB=2, WELEM=2048
    if (e < 36864){
      int k = e/4096, plane = (e%4096)/2048, r = e%2048;
      int kb = r/1024, r2 = r%1024;
      int n0 = r2>>9, q = r2&511, l = q>>3, j = q&7;
      int co = n0*16 + (l&15), c = kb*32 + (l>>4)*8 + j;
      float w = (co < 18) ? ow1[(co*64 + c)*9 + k] : (co < 27 ? mw1[((co-18)*64 + c)*9 + k] : 0.f);
      us hi = f2bf(w), lo = f2bf(w - bf2f(hi));
      a1[e] = plane ? lo : hi;
    }
  }
  { // aux2: CIN=128, NT=2, KB=4, WELEM=4096
    if (e < 73728){
      int k = e/8192, plane = (e%8192)/4096, r = e%4096;
      int kb = r/1024, r2 = r%1024;
      int n0 = r2>>9, q = r2&511, l = q>>3, j = q&7;
      int co = n0*16 + (l&15), c = kb*32 + (l>>4)*8 + j;
      float w = (co < 18) ? ow2[(co*128 + c)*9 + k] : (co < 27 ? mw2[((co-18)*128 + c)*9 + k] : 0.f);
      us hi = f2bf(w), lo = f2bf(w - bf2f(hi));
      a2[e] = plane ? lo : hi;
    }
  }
}

// ---------------------------------------------------------------- fused aux conv + deformable conv
// One block = one (b, ho) output row. Phase A: aux 3x3 conv (27ch) -> LDS.
// Tables: bilinear corner offsets + mask-folded weights. Phase B: deform conv,
// A-fragments gathered DIRECTLY global->registers (lane-local bilinear+split),
// B-fragments streamed from fragment-linear global tables (L2-hot). No per-tap barriers.
// STAGE 1: BN+ReLU -> f32 NHWC out.  STAGE 2: per-(b,ho) column sums.
template<int CIN, int STAGE>
__global__ __launch_bounds__(256, 3) void k_fused(
    const float* __restrict__ inT,
    const us* __restrict__ wb_aux, const us* __restrict__ wb_def,
    const float* __restrict__ bn_g, const float* __restrict__ bn_b,
    const float* __restrict__ bn_m, const float* __restrict__ bn_v,
    float* __restrict__ outT, float* __restrict__ partial){
  constexpr int KB   = CIN/32;
  constexpr int WE_A = 2*KB*512;
  constexpr int WE_D = 8*KB*512;
  __shared__ uint2  otab[576];
  __shared__ float4 wtab[576];
  __shared__ float  am[27*66];
  __shared__ float  extra[256];

  const int id  = blockIdx.x;
  const int nid = (id & 7)*128 + (id >> 3);      // XCD swizzle (1024 % 8 == 0, bijective)
  const int b = nid >> 6, ho = nid & 63;
  const int tid = threadIdx.x;
  const float* __restrict__ inb = inT + (size_t)b*4096*CIN;

  if (STAGE == 1 && tid < 128){
    float inv = rsqrtf(bn_v[tid] + 1e-5f)*bn_g[tid];
    extra[tid] = inv; extra[128 + tid] = bn_b[tid] - bn_m[tid]*inv;
  }

  const int lane = tid & 63, lr = lane & 15, lg = lane >> 4;
  const int wv = tid >> 6, mh = wv & 1, nh = wv >> 1;
  const int ch_off = lg*8;

  // ===== phase A: aux conv (integer taps, direct-to-register) =====
  f32x4 aacc0 = (f32x4){0.f,0.f,0.f,0.f}, aacc1 = (f32x4){0.f,0.f,0.f,0.f};
  for (int k = 0; k < 9; ++k){
    const int kh = k/3, kw = k - kh*3;
    const int y = ho - 1 + kh;
    const float fy = (y >= 0 && y < 64) ? 1.f : 0.f;
    const int yc = min(max(y, 0), 63);
    const us* wk = wb_aux + (size_t)(k*2)*WE_A;
    for (int kb = 0; kb < KB; ++kb){
      const int c0 = kb*32 + ch_off;
      bf16x8 ah[2], al[2];
      #pragma unroll
      for (int m = 0; m < 2; ++m){
        const int px = mh*32 + m*16 + lr;
        const int x = px - 1 + kw;
        const float wf = fy * ((x >= 0 && x < 64) ? 1.f : 0.f);
        const float* src = inb + (size_t)(yc*64 + min(max(x,0),63))*CIN + c0;
        const float4 q0 = *(const float4*)src;
        const float4 q1 = *(const float4*)(src + 4);
        float vv[8] = {q0.x*wf, q0.y*wf, q0.z*wf, q0.w*wf,
                       q1.x*wf, q1.y*wf, q1.z*wf, q1.w*wf};
        split_pack(vv, ah[m], al[m]);
      }
      const us* bp = wk + (size_t)(kb*2 + nh)*512 + lane*8;
      bf16x8 bh = *(const bf16x8*)bp;
      bf16x8 bl = *(const bf16x8*)(bp + WE_A);
      aacc0 = MFMA16(ah[0], bh, aacc0); aacc0 = MFMA16(al[0], bh, aacc0); aacc0 = MFMA16(ah[0], bl, aacc0);
      aacc1 = MFMA16(ah[1], bh, aacc1); aacc1 = MFMA16(al[1], bh, aacc1); aacc1 = MFMA16(ah[1], bl, aacc1);
    }
  }
  {
    const int co = nh*16 + lr;
    if (co < 27){
      #pragma unroll
      for (int i = 0; i < 4; ++i){
        am[co*66 + mh*32      + lg*4 + i] = aacc0[i];
        am[co*66 + mh*32 + 16 + lg*4 + i] = aacc1[i];
      }
    }
  }
  __syncthreads();

  // ===== build bilinear tables from aux outputs =====
  for (int it = 0; it < 3; ++it){
    int sid = it*256 + tid;
    if (sid < 576){
      int k = sid >> 6, px = sid & 63;
      int kh = k/3, kw = k - kh*3;
      float oy = am[(2*k)*66 + px];
      float ox = am[(2*k+1)*66 + px];
      float mv = 1.f/(1.f + expf(-am[(18+k)*66 + px]));
      float py  = (float)(ho - 1 + kh) + oy;
      float pxx = (float)(px - 1 + kw) + ox;
      float fyf = floorf(py), fxf = floorf(pxx);
      int y0 = (int)fyf, x0 = (int)fxf;
      float dy = py - fyf, dx = pxx - fxf;
      bool vy0 = (y0 >= 0) && (y0 < 64), vy1 = (y0 >= -1) && (y0 < 63);
      bool vx0 = (x0 >= 0) && (x0 < 64), vx1 = (x0 >= -1) && (x0 < 63);
      int y0c = min(max(y0,0),63), y1c = min(max(y0+1,0),63);
      int x0c = min(max(x0,0),63), x1c = min(max(x0+1,0),63);
      otab[sid] = make_uint2((unsigned)(y0c*64 + x0c) | ((unsigned)(y0c*64 + x1c) << 16),
                             (unsigned)(y1c*64 + x0c) | ((unsigned)(y1c*64 + x1c) << 16));
      wtab[sid] = make_float4((1.f-dy)*(1.f-dx)*mv*((vy0 && vx0) ? 1.f : 0.f),
                              (1.f-dy)*dx     *mv*((vy0 && vx1) ? 1.f : 0.f),
                              dy*(1.f-dx)     *mv*((vy1 && vx0) ? 1.f : 0.f),
                              dy*dx           *mv*((vy1 && vx1) ? 1.f : 0.f));
    }
  }
  __syncthreads();

  // ===== phase B: deformable conv, direct-to-register gather =====
  f32x4 acc[2][4];
  #pragma unroll
  for (int m = 0; m < 2; ++m)
    #pragma unroll
    for (int n = 0; n < 4; ++n) acc[m][n] = (f32x4){0.f,0.f,0.f,0.f};

  for (int k = 0; k < 9; ++k){
    const us* wk = wb_def + (size_t)(k*2)*WE_D;
    for (int kb = 0; kb < KB; ++kb){
      const int c0 = kb*32 + ch_off;
      bf16x8 ah[2], al[2];
      #pragma unroll
      for (int m = 0; m < 2; ++m){
        const int px = mh*32 + m*16 + lr;
        const uint2 o = otab[k*64 + px];
        const float4 w4 = wtab[k*64 + px];
        const float* pA = inb + (size_t)(o.x & 0xffffu)*CIN + c0;
        const float* pB = inb + (size_t)(o.x >> 16)    *CIN + c0;
        const float* pC = inb + (size_t)(o.y & 0xffffu)*CIN + c0;
        const float* pD = inb + (size_t)(o.y >> 16)    *CIN + c0;
        const float4 qa0 = *(const float4*)pA, qa1 = *(const float4*)(pA + 4);
        const float4 qb0 = *(const float4*)pB, qb1 = *(const float4*)(pB + 4);
        const float4 qc0 = *(const float4*)pC, qc1 = *(const float4*)(pC + 4);
        const float4 qd0 = *(const float4*)pD, qd1 = *(const float4*)(pD + 4);
        float vv[8];
        vv[0] = w4.x*qa0.x + w4.y*qb0.x + w4.z*qc0.x + w4.w*qd0.x;
        vv[1] = w4.x*qa0.y + w4.y*qb0.y + w4.z*qc0.y + w4.w*qd0.y;
        vv[2] = w4.x*qa0.z + w4.y*qb0.z + w4.z*qc0.z + w4.w*qd0.z;
        vv[3] = w4.x*qa0.w + w4.y*qb0.w + w4.z*qc0.w + w4.w*qd0.w;
        vv[4] = w4.x*qa1.x + w4.y*qb1.x + w4.z*qc1.x + w4.w*qd1.x;
        vv[5] = w4.x*qa1.y + w4.y*qb1.y + w4.z*qc1.y + w4.w*qd1.y;
        vv[6] = w4.x*qa1.z + w4.y*qb1.z + w4.z*qc1.z + w4.w*qd1.z;
        vv[7] = w4.x*qa1.w + w4.y*qb1.w + w4.z*qc1.w + w4.w*qd1.w;
        split_pack(vv, ah[m], al[m]);
      }
      #pragma unroll
      for (int nt = 0; nt < 4; ++nt){
        const us* bp = wk + (size_t)(kb*8 + nh*4 + nt)*512 + lane*8;
        bf16x8 bh = *(const bf16x8*)bp;
        bf16x8 bl = *(const bf16x8*)(bp + WE_D);
        acc[0][nt] = MFMA16(ah[0], bh, acc[0][nt]);
        acc[0][nt] = MFMA16(al[0], bh, acc[0][nt]);
        acc[0][nt] = MFMA16(ah[0], bl, acc[0][nt]);
        acc[1][nt] = MFMA16(ah[1], bh, acc[1][nt]);
        acc[1][nt] = MFMA16(al[1], bh, acc[1][nt]);
        acc[1][nt] = MFMA16(ah[1], bl, acc[1][nt]);
      }
    }
  }

  // ===== epilogue =====
  if (STAGE == 1){
    const size_t rowbase = (size_t)(b*4096 + ho*64)*128;
    #pragma unroll
    for (int mt = 0; mt < 2; ++mt){
      const int pxl = mh*32 + mt*16 + lg*4;
      #pragma unroll
      for (int nt = 0; nt < 4; ++nt){
        const int co = nh*64 + nt*16 + lr;
        const float inv = extra[co], bia = extra[128 + co];
        #pragma unroll
        for (int i = 0; i < 4; ++i){
          float v = acc[mt][nt][i]*inv + bia;
          outT[rowbase + (size_t)(pxl + i)*128 + co] = fmaxf(v, 0.f);
        }
      }
    }
  } else {
    #pragma unroll
    for (int nt = 0; nt < 4; ++nt){
      float s = acc[0][nt][0] + acc[0][nt][1] + acc[0][nt][2] + acc[0][nt][3]
              + acc[1][nt][0] + acc[1][nt][1] + acc[1][nt][2] + acc[1][nt][3];
      s += __shfl_xor(s, 16);
      s += __shfl_xor(s, 32);
      if (lane < 16) extra[mh*128 + nh*64 + nt*16 + lane] = s;
    }
    __syncthreads();
    if (tid < 128) partial[(size_t)(b*64 + ho)*128 + tid] = extra[tid] + extra[128 + tid];
  }
}

// ---------------------------------------------------------------- pool + BN2 fold
__global__ __launch_bounds__(256) void k_pool(
    const float* __restrict__ partial,
    const float* __restrict__ g2, const float* __restrict__ b2,
    const float* __restrict__ m2, const float* __restrict__ v2,
    float* __restrict__ pooled){
  const int t = blockIdx.x*TPB + threadIdx.x;
  if (t >= 2048) return;
  const int b = t >> 7, c = t & 127;
  float s = 0.f;
  for (int h = 0; h < 64; ++h) s += partial[(b*64 + h)*128 + c];
  const float inv = rsqrtf(v2[c] + 1e-5f)*g2[c];
  pooled[t] = s*(1.f/4096.f)*inv + (b2[c] - m2[c]*inv);
}

// ---------------------------------------------------------------- fc
__global__ __launch_bounds__(256) void k_fc(
    const float* __restrict__ pooled, const float* __restrict__ fcw,
    const float* __restrict__ fcb, float* __restrict__ outp){
  const int t = blockIdx.x*TPB + threadIdx.x;
  if (t >= 16000) return;
  const int b = t/1000, n = t - b*1000;
  const float* p = pooled + b*128;
  const float* w = fcw + n*128;
  float s = fcb[n];
  #pragma unroll
  for (int c = 0; c < 128; c += 4){
    const float4 pv = *(const float4*)(p + c);
    const float4 wv = *(const float4*)(w + c);
    s = fmaf(pv.x, wv.x, s); s = fmaf(pv.y, wv.y, s);
    s = fmaf(pv.z, wv.z, s); s = fmaf(pv.w, wv.w, s);
  }
  outp[t] = s;
}

extern "C" void kernel_launch(void* const* d_in, const int* in_sizes, int n_in,
                              void* d_out, int out_size, void* d_ws, size_t ws_size,
                              hipStream_t stream){
  const float* x      = (const float*)d_in[0];
  const float* conv1w = (const float*)d_in[1];
  const float* off1w  = (const float*)d_in[2];
  const float* mod1w  = (const float*)d_in[3];
  const float* bn1g   = (const float*)d_in[4];
  const float* bn1b   = (const float*)d_in[5];
  const float* bn1m   = (const float*)d_in[6];
  const float* bn1v   = (const float*)d_in[7];
  const float* conv2w = (const float*)d_in[8];
  const float* off2w  = (const float*)d_in[9];
  const float* mod2w  = (const float*)d_in[10];
  const float* bn2g   = (const float*)d_in[11];
  const float* bn2b   = (const float*)d_in[12];
  const float* bn2m   = (const float*)d_in[13];
  const float* bn2v   = (const float*)d_in[14];
  const float* fcw    = (const float*)d_in[15];
  const float* fcb    = (const float*)d_in[16];

  char* w = (char*)d_ws;
  float* xT      = (float*)(w);                   // 16,777,216 B
  float* out1T   = (float*)(w + 16777216);        // 33,554,432 B
  float* partial = (float*)(w + 50331648);        //    524,288 B
  float* pooled  = (float*)(w + 50855936);        //      8,192 B
  us*    wb_d1   = (us*)(w + 50864128);           //    294,912 B
  us*    wb_d2   = (us*)(w + 51159040);           //    589,824 B
  us*    wb_a1   = (us*)(w + 51748864);           //     73,728 B
  us*    wb_a2   = (us*)(w + 51822592);           //    147,456 B

  k_transpose_x<<<dim3(64,16), TPB, 0, stream>>>(x, xT);
  k_prep<<<1152, TPB, 0, stream>>>(conv1w, off1w, mod1w, conv2w, off2w, mod2w,
                                   wb_d1, wb_d2, wb_a1, wb_a2);

  k_fused<64,1><<<1024, TPB, 0, stream>>>(
      xT, wb_a1, wb_d1, bn1g, bn1b, bn1m, bn1v, out1T, nullptr);
  k_fused<128,2><<<1024, TPB, 0, stream>>>(
      out1T, wb_a2, wb_d2, nullptr, nullptr, nullptr, nullptr, nullptr, partial);

  k_pool<<<8, TPB, 0, stream>>>(partial, bn2g, bn2b, bn2m, bn2v, pooled);
  k_fc<<<63, TPB, 0, stream>>>(pooled, fcw, fcb, (float*)d_out);
}

// Round 6
// 221.412 us; speedup vs baseline: 2.3926x; 2.3926x over previous
//
#include <hip/hip_runtime.h>
#include <hip/hip_bf16.h>

#define TPB 256
typedef unsigned short us;
typedef __attribute__((ext_vector_type(8))) short bf16x8;
typedef __attribute__((ext_vector_type(4))) float f32x4;

__device__ inline us f2bf(float f){ union{ __hip_bfloat16 h; us s; } x; x.h = __float2bfloat16(f); return x.s; }
__device__ inline float bf2f(us u){ union{unsigned v; float f;} x; x.v = ((unsigned)u)<<16; return x.f; }
#define MFMA16(a,b,c) __builtin_amdgcn_mfma_f32_16x16x32_bf16((a),(b),(c),0,0,0)

// ---------------------------------------------------------------- x NCHW f32 -> NHWC f32
__global__ __launch_bounds__(256) void k_transpose_x(const float* __restrict__ x,
                                                     float* __restrict__ xT){
  __shared__ float tile[64][65];
  const int y = blockIdx.x, b = blockIdx.y;
  for (int i = threadIdx.x; i < 4096; i += TPB){
    const int c = i >> 6, xx = i & 63;
    tile[c][xx] = x[b*262144 + c*4096 + y*64 + xx];
  }
  __syncthreads();
  for (int i = threadIdx.x; i < 4096; i += TPB){
    const int xx = i >> 6, c = i & 63;
    xT[(size_t)(b*4096 + y*64 + xx)*64 + c] = tile[c][xx];
  }
}

// ---------------------------------------------------------------- weights -> fragment-linear split-bf16
// per table: [k(9)][plane(2: hi,lo)][kb][n0][lane(64)][j(8)]
// elem = W[co = n0*16+(l&15)][c = kb*32+(l>>4)*8+j][k]
__global__ __launch_bounds__(256) void k_prep(
    const float* __restrict__ cw1, const float* __restrict__ ow1, const float* __restrict__ mw1,
    const float* __restrict__ cw2, const float* __restrict__ ow2, const float* __restrict__ mw2,
    us* __restrict__ d1, us* __restrict__ d2, us* __restrict__ a1, us* __restrict__ a2){
  const int e = blockIdx.x*TPB + threadIdx.x;
  { // deform1: CIN=64, NT=8, KB=2, WELEM=8192
    if (e < 147456){
      int k = e/16384, plane = (e%16384)/8192, r = e%8192;
      int kb = r/4096, r2 = r%4096;
      int n0 = r2>>9, q = r2&511, l = q>>3, j = q&7;
      int co = n0*16 + (l&15), c = kb*32 + (l>>4)*8 + j;
      float w = cw1[(co*64 + c)*9 + k];
      us hi = f2bf(w), lo = f2bf(w - bf2f(hi));
      d1[e] = plane ? lo : hi;
    }
  }
  { // deform2: CIN=128, NT=8, KB=4, WELEM=16384
    if (e < 294912){
      int k = e/32768, plane = (e%32768)/16384, r = e%16384;
      int kb = r/4096, r2 = r%4096;
      int n0 = r2>>9, q = r2&511, l = q>>3, j = q&7;
      int co = n0*16 + (l&15), c = kb*32 + (l>>4)*8 + j;
      float w = cw2[(co*128 + c)*9 + k];
      us hi = f2bf(w), lo = f2bf(w - bf2f(hi));
      d2[e] = plane ? lo : hi;
    }
  }
  { // aux1: CIN=64, NT=2, KB=2, WELEM=2048
    if (e < 36864){
      int k = e/4096, plane = (e%4096)/2048, r = e%2048;
      int kb = r/1024, r2 = r%1024;
      int n0 = r2>>9, q = r2&511, l = q>>3, j = q&7;
      int co = n0*16 + (l&15), c = kb*32 + (l>>4)*8 + j;
      float w = (co < 18) ? ow1[(co*64 + c)*9 + k] : (co < 27 ? mw1[((co-18)*64 + c)*9 + k] : 0.f);
      us hi = f2bf(w), lo = f2bf(w - bf2f(hi));
      a1[e] = plane ? lo : hi;
    }
  }
  { // aux2: CIN=128, NT=2, KB=4, WELEM=4096
    if (e < 73728){
      int k = e/8192, plane = (e%8192)/4096, r = e%4096;
      int kb = r/1024, r2 = r%1024;
      int n0 = r2>>9, q = r2&511, l = q>>3, j = q&7;
      int co = n0*16 + (l&15), c = kb*32 + (l>>4)*8 + j;
      float w = (co < 18) ? ow2[(co*128 + c)*9 + k] : (co < 27 ? mw2[((co-18)*128 + c)*9 + k] : 0.f);
      us hi = f2bf(w), lo = f2bf(w - bf2f(hi));
      a2[e] = plane ? lo : hi;
    }
  }
}

// ---------------------------------------------------------------- fused aux + deformable conv
// One block = one (b, ho). Phase A: aux 3x3 conv, 3 input rows (+halo) row-staged in LDS
// per 32-ch chunk, MFMA over 9 taps -> 27 aux channels in LDS.  Tables: bilinear corners
// + mask-folded weights.  Phase B: deform conv, per-(tap,32ch) chunks staged cooperatively
// into double-buffered LDS (stage(i+1) issued before MFMA(i), 1 barrier/chunk).
// Waves partition N (each wave: 2 of 8 co-tiles, all 4 M-tiles) -> B fragments read once.
// STAGE 1: BN+ReLU -> f32 NHWC.  STAGE 2: per-(b,ho) column sums.
template<int CIN, int STAGE>
__global__ __launch_bounds__(256, 3) void k_fused(
    const float* __restrict__ inT,
    const us* __restrict__ wb_aux, const us* __restrict__ wb_def,
    const float* __restrict__ bn_g, const float* __restrict__ bn_b,
    const float* __restrict__ bn_m, const float* __restrict__ bn_v,
    float* __restrict__ outT, float* __restrict__ partial){
  constexpr int KB   = CIN/32;
  constexpr int NC   = 9*KB;
  constexpr int WE_A = 2*KB*512;
  constexpr int WE_D = 8*KB*512;

  // pool aliases: phase A rows (2 planes x 3*66 slots x 40 us = 31680 B)
  //               then am[27*66] f32, then phase B g[2 buf][2 plane][64*40 us]
  __shared__ __align__(16) us pool[15840];
  __shared__ uint2  otab[576];
  __shared__ float4 wtab[576];
  __shared__ float  extra[256];

  const int id  = blockIdx.x;
  const int nid = (id & 7)*128 + (id >> 3);      // XCD swizzle (1024 % 8 == 0, bijective)
  const int b = nid >> 6, ho = nid & 63;
  const int tid = threadIdx.x;
  const float* __restrict__ inb = inT + (size_t)b*4096*CIN;

  if (STAGE == 1 && tid < 128){
    float inv = rsqrtf(bn_v[tid] + 1e-5f)*bn_g[tid];
    extra[tid] = inv; extra[128 + tid] = bn_b[tid] - bn_m[tid]*inv;
  }

  const int lane = tid & 63, lr = lane & 15, lg = lane >> 4;
  const int wv = tid >> 6;
  const int ch_off = lg*8;

  // ===== phase A: aux conv, row-staged =====
  us* rhi = pool;            // [3*66][40]
  us* rlo = pool + 7920;
  f32x4 aacc[2];
  aacc[0] = (f32x4){0.f,0.f,0.f,0.f}; aacc[1] = (f32x4){0.f,0.f,0.f,0.f};

  for (int kb = 0; kb < KB; ++kb){
    if (kb) __syncthreads();               // protect rows from previous kb's reads
    for (int s = tid; s < 1584; s += 256){ // 3*66 slots x 8 ch-quads
      const int cq = s & 7, slot = s >> 3;
      const int r = slot/66, p = slot - r*66;
      const int y = ho - 1 + r, x = p - 1;
      const bool ok = (y >= 0) && (y < 64) && (x >= 0) && (x < 64);
      float4 q = make_float4(0.f,0.f,0.f,0.f);
      if (ok) q = *(const float4*)(inb + (size_t)(y*64 + x)*CIN + kb*32 + cq*4);
      us h0 = f2bf(q.x), h1 = f2bf(q.y), h2 = f2bf(q.z), h3 = f2bf(q.w);
      us l0 = f2bf(q.x - bf2f(h0)), l1 = f2bf(q.y - bf2f(h1));
      us l2 = f2bf(q.z - bf2f(h2)), l3 = f2bf(q.w - bf2f(h3));
      *(uint2*)(rhi + slot*40 + cq*4) = make_uint2((unsigned)h0 | ((unsigned)h1<<16),
                                                   (unsigned)h2 | ((unsigned)h3<<16));
      *(uint2*)(rlo + slot*40 + cq*4) = make_uint2((unsigned)l0 | ((unsigned)l1<<16),
                                                   (unsigned)l2 | ((unsigned)l3<<16));
    }
    __syncthreads();
    #pragma unroll
    for (int k = 0; k < 9; ++k){
      const int kh = k/3, kw = k - kh*3;
      const int off = (kh*66 + wv*16 + lr + kw)*40 + ch_off;
      bf16x8 ah = *(const bf16x8*)(rhi + off);
      bf16x8 al = *(const bf16x8*)(rlo + off);
      #pragma unroll
      for (int n = 0; n < 2; ++n){
        const us* bp = wb_aux + (size_t)k*2*WE_A + (size_t)(kb*2 + n)*512 + lane*8;
        bf16x8 bh = *(const bf16x8*)bp;
        bf16x8 bl = *(const bf16x8*)(bp + WE_A);
        aacc[n] = MFMA16(ah, bh, aacc[n]);
        aacc[n] = MFMA16(al, bh, aacc[n]);
        aacc[n] = MFMA16(ah, bl, aacc[n]);
      }
    }
  }
  __syncthreads();                          // rows dead; am may alias

  float* am = (float*)pool;                 // [27][66]
  #pragma unroll
  for (int n = 0; n < 2; ++n){
    const int co = n*16 + lr;
    if (co < 27){
      #pragma unroll
      for (int i = 0; i < 4; ++i) am[co*66 + wv*16 + lg*4 + i] = aacc[n][i];
    }
  }
  __syncthreads();

  // ===== bilinear tables =====
  for (int it = 0; it < 3; ++it){
    const int sid = it*256 + tid;
    if (sid < 576){
      const int k = sid >> 6, px = sid & 63;
      const int kh = k/3, kw = k - kh*3;
      float oy = am[(2*k)*66 + px];
      float ox = am[(2*k+1)*66 + px];
      float mv = 1.f/(1.f + expf(-am[(18+k)*66 + px]));
      float py  = (float)(ho - 1 + kh) + oy;
      float pxx = (float)(px - 1 + kw) + ox;
      float fyf = floorf(py), fxf = floorf(pxx);
      int y0 = (int)fyf, x0 = (int)fxf;
      float dy = py - fyf, dx = pxx - fxf;
      bool vy0 = (y0 >= 0) && (y0 < 64), vy1 = (y0 >= -1) && (y0 < 63);
      bool vx0 = (x0 >= 0) && (x0 < 64), vx1 = (x0 >= -1) && (x0 < 63);
      int y0c = min(max(y0,0),63), y1c = min(max(y0+1,0),63);
      int x0c = min(max(x0,0),63), x1c = min(max(x0+1,0),63);
      otab[sid] = make_uint2((unsigned)(y0c*64 + x0c) | ((unsigned)(y0c*64 + x1c) << 16),
                             (unsigned)(y1c*64 + x0c) | ((unsigned)(y1c*64 + x1c) << 16));
      wtab[sid] = make_float4((1.f-dy)*(1.f-dx)*mv*((vy0 && vx0) ? 1.f : 0.f),
                              (1.f-dy)*dx     *mv*((vy0 && vx1) ? 1.f : 0.f),
                              dy*(1.f-dx)     *mv*((vy1 && vx0) ? 1.f : 0.f),
                              dy*dx           *mv*((vy1 && vx1) ? 1.f : 0.f));
    }
  }
  __syncthreads();                          // am dead; g buffers may alias

  // ===== phase B: deform conv, double-buffered chunks =====
  f32x4 acc[4][2];
  #pragma unroll
  for (int m = 0; m < 4; ++m){ acc[m][0] = (f32x4){0.f,0.f,0.f,0.f}; acc[m][1] = (f32x4){0.f,0.f,0.f,0.f}; }

  auto stage_def = [&](int i, us* dhi, us* dlo){
    const int k = i/KB, kb = i - (i/KB)*KB;
    #pragma unroll
    for (int it = 0; it < 2; ++it){
      const int s = it*256 + tid;
      const int px = s >> 3, cq = s & 7;
      const uint2 o = otab[k*64 + px];
      const float4 w4 = wtab[k*64 + px];
      const int c0 = kb*32 + cq*4;
      const float4 qa = *(const float4*)(inb + (size_t)(o.x & 0xffffu)*CIN + c0);
      const float4 qb = *(const float4*)(inb + (size_t)(o.x >> 16)    *CIN + c0);
      const float4 qc = *(const float4*)(inb + (size_t)(o.y & 0xffffu)*CIN + c0);
      const float4 qd = *(const float4*)(inb + (size_t)(o.y >> 16)    *CIN + c0);
      float v0 = w4.x*qa.x + w4.y*qb.x + w4.z*qc.x + w4.w*qd.x;
      float v1 = w4.x*qa.y + w4.y*qb.y + w4.z*qc.y + w4.w*qd.y;
      float v2 = w4.x*qa.z + w4.y*qb.z + w4.z*qc.z + w4.w*qd.z;
      float v3 = w4.x*qa.w + w4.y*qb.w + w4.z*qc.w + w4.w*qd.w;
      us h0 = f2bf(v0), h1 = f2bf(v1), h2 = f2bf(v2), h3 = f2bf(v3);
      us l0 = f2bf(v0 - bf2f(h0)), l1 = f2bf(v1 - bf2f(h1));
      us l2 = f2bf(v2 - bf2f(h2)), l3 = f2bf(v3 - bf2f(h3));
      *(uint2*)(dhi + px*40 + cq*4) = make_uint2((unsigned)h0 | ((unsigned)h1<<16),
                                                 (unsigned)h2 | ((unsigned)h3<<16));
      *(uint2*)(dlo + px*40 + cq*4) = make_uint2((unsigned)l0 | ((unsigned)l1<<16),
                                                 (unsigned)l2 | ((unsigned)l3<<16));
    }
  };
  auto mfma_def = [&](int i, const us* shi, const us* slo){
    const int k = i/KB, kb = i - (i/KB)*KB;
    bf16x8 ah[4], al[4];
    #pragma unroll
    for (int mt = 0; mt < 4; ++mt){
      const int off = (mt*16 + lr)*40 + ch_off;
      ah[mt] = *(const bf16x8*)(shi + off);
      al[mt] = *(const bf16x8*)(slo + off);
    }
    #pragma unroll
    for (int nt = 0; nt < 2; ++nt){
      const int n0 = wv*2 + nt;
      const us* bp = wb_def + (size_t)k*2*WE_D + (size_t)(kb*8 + n0)*512 + lane*8;
      bf16x8 bh = *(const bf16x8*)bp;
      bf16x8 bl = *(const bf16x8*)(bp + WE_D);
      #pragma unroll
      for (int mt = 0; mt < 4; ++mt){
        acc[mt][nt] = MFMA16(ah[mt], bh, acc[mt][nt]);
        acc[mt][nt] = MFMA16(al[mt], bh, acc[mt][nt]);
        acc[mt][nt] = MFMA16(ah[mt], bl, acc[mt][nt]);
      }
    }
  };
  // g(buf d, plane p) at pool + (d*2+p)*2560
  stage_def(0, pool, pool + 2560);
  __syncthreads();
  for (int i = 0; i < NC; ++i){
    const int cur = (i & 1)*2;
    const int nxt = ((i+1) & 1)*2;
    if (i + 1 < NC) stage_def(i+1, pool + nxt*2560, pool + (nxt+1)*2560);
    mfma_def(i, pool + cur*2560, pool + (cur+1)*2560);
    __syncthreads();
  }

  // ===== epilogue =====
  if (STAGE == 1){
    const size_t rowbase = (size_t)(b*4096 + ho*64)*128;
    #pragma unroll
    for (int mt = 0; mt < 4; ++mt){
      const int pxl = mt*16 + lg*4;
      #pragma unroll
      for (int nt = 0; nt < 2; ++nt){
        const int co = (wv*2 + nt)*16 + lr;
        const float inv = extra[co], bia = extra[128 + co];
        #pragma unroll
        for (int i = 0; i < 4; ++i){
          float v = acc[mt][nt][i]*inv + bia;
          outT[rowbase + (size_t)(pxl + i)*128 + co] = fmaxf(v, 0.f);
        }
      }
    }
  } else {
    #pragma unroll
    for (int nt = 0; nt < 2; ++nt){
      float s = 0.f;
      #pragma unroll
      for (int mt = 0; mt < 4; ++mt)
        s += acc[mt][nt][0] + acc[mt][nt][1] + acc[mt][nt][2] + acc[mt][nt][3];
      s += __shfl_xor(s, 16);
      s += __shfl_xor(s, 32);
      if (lane < 16) extra[(wv*2 + nt)*16 + lane] = s;
    }
    __syncthreads();
    if (tid < 128) partial[(size_t)(b*64 + ho)*128 + tid] = extra[tid];
  }
}

// ---------------------------------------------------------------- pool + BN2 fold
__global__ __launch_bounds__(256) void k_pool(
    const float* __restrict__ partial,
    const float* __restrict__ g2, const float* __restrict__ b2,
    const float* __restrict__ m2, const float* __restrict__ v2,
    float* __restrict__ pooled){
  const int t = blockIdx.x*TPB + threadIdx.x;
  if (t >= 2048) return;
  const int b = t >> 7, c = t & 127;
  float s = 0.f;
  for (int h = 0; h < 64; ++h) s += partial[(b*64 + h)*128 + c];
  const float inv = rsqrtf(v2[c] + 1e-5f)*g2[c];
  pooled[t] = s*(1.f/4096.f)*inv + (b2[c] - m2[c]*inv);
}

// ---------------------------------------------------------------- fc
__global__ __launch_bounds__(256) void k_fc(
    const float* __restrict__ pooled, const float* __restrict__ fcw,
    const float* __restrict__ fcb, float* __restrict__ outp){
  const int t = blockIdx.x*TPB + threadIdx.x;
  if (t >= 16000) return;
  const int b = t/1000, n = t - b*1000;
  const float* p = pooled + b*128;
  const float* w = fcw + n*128;
  float s = fcb[n];
  #pragma unroll
  for (int c = 0; c < 128; c += 4){
    const float4 pv = *(const float4*)(p + c);
    const float4 wv = *(const float4*)(w + c);
    s = fmaf(pv.x, wv.x, s); s = fmaf(pv.y, wv.y, s);
    s = fmaf(pv.z, wv.z, s); s = fmaf(pv.w, wv.w, s);
  }
  outp[t] = s;
}

extern "C" void kernel_launch(void* const* d_in, const int* in_sizes, int n_in,
                              void* d_out, int out_size, void* d_ws, size_t ws_size,
                              hipStream_t stream){
  const float* x      = (const float*)d_in[0];
  const float* conv1w = (const float*)d_in[1];
  const float* off1w  = (const float*)d_in[2];
  const float* mod1w  = (const float*)d_in[3];
  const float* bn1g   = (const float*)d_in[4];
  const float* bn1b   = (const float*)d_in[5];
  const float* bn1m   = (const float*)d_in[6];
  const float* bn1v   = (const float*)d_in[7];
  const float* conv2w = (const float*)d_in[8];
  const float* off2w  = (const float*)d_in[9];
  const float* mod2w  = (const float*)d_in[10];
  const float* bn2g   = (const float*)d_in[11];
  const float* bn2b   = (const float*)d_in[12];
  const float* bn2m   = (const float*)d_in[13];
  const float* bn2v   = (const float*)d_in[14];
  const float* fcw    = (const float*)d_in[15];
  const float* fcb    = (const float*)d_in[16];

  char* w = (char*)d_ws;
  float* xT      = (float*)(w);                   // 16,777,216 B
  float* out1T   = (float*)(w + 16777216);        // 33,554,432 B
  float* partial = (float*)(w + 50331648);        //    524,288 B
  float* pooled  = (float*)(w + 50855936);        //      8,192 B
  us*    wb_d1   = (us*)(w + 50864128);           //    294,912 B
  us*    wb_d2   = (us*)(w + 51159040);           //    589,824 B
  us*    wb_a1   = (us*)(w + 51748864);           //     73,728 B
  us*    wb_a2   = (us*)(w + 51822592);           //    147,456 B

  k_transpose_x<<<dim3(64,16), TPB, 0, stream>>>(x, xT);
  k_prep<<<1152, TPB, 0, stream>>>(conv1w, off1w, mod1w, conv2w, off2w, mod2w,
                                   wb_d1, wb_d2, wb_a1, wb_a2);

  k_fused<64,1><<<1024, TPB, 0, stream>>>(
      xT, wb_a1, wb_d1, bn1g, bn1b, bn1m, bn1v, out1T, nullptr);
  k_fused<128,2><<<1024, TPB, 0, stream>>>(
      out1T, wb_a2, wb_d2, nullptr, nullptr, nullptr, nullptr, nullptr, partial);

  k_pool<<<8, TPB, 0, stream>>>(partial, bn2g, bn2b, bn2m, bn2v, pooled);
  k_fc<<<63, TPB, 0, stream>>>(pooled, fcw, fcb, (float*)d_out);
}

// Round 7
// 112.459 us; speedup vs baseline: 4.7106x; 1.9688x over previous
//
#include <hip/hip_runtime.h>

#define TPB 256
typedef unsigned short us;
typedef __attribute__((ext_vector_type(8))) _Float16 f16x8;
typedef __attribute__((ext_vector_type(2))) _Float16 f16x2;
typedef __attribute__((ext_vector_type(4))) float f32x4;

__device__ inline us f2h(float f){ union{ _Float16 h; us u; } x; x.h = (_Float16)f; return x.u; }
__device__ inline f16x2 u2h2(unsigned u){ union{ unsigned v; f16x2 h; } x; x.v = u; return x.h; }
#define MFMA16(a,b,c) __builtin_amdgcn_mfma_f32_16x16x32_f16((a),(b),(c),0,0,0)
#define PERM_LO 0x01000504u   // (A.lo16, B.lo16)
#define PERM_HI 0x03020706u   // (A.hi16, B.hi16)
__device__ inline int swz(int row, int q){ return q ^ ((row ^ (row >> 2)) & 3); }

// ---------------------------------------------------------------- x NCHW f32 -> NHWC f16
__global__ __launch_bounds__(256) void k_transpose_x(const float* __restrict__ x,
                                                     us* __restrict__ xT){
  __shared__ float tile[64][65];
  const int y = blockIdx.x, b = blockIdx.y;
  for (int i = threadIdx.x; i < 4096; i += TPB){
    const int c = i >> 6, xx = i & 63;
    tile[c][xx] = x[b*262144 + c*4096 + y*64 + xx];
  }
  __syncthreads();
  for (int i = threadIdx.x; i < 4096; i += TPB){
    const int xx = i >> 6, c = i & 63;
    xT[(size_t)(b*4096 + y*64 + xx)*64 + c] = f2h(tile[c][xx]);
  }
}

// ---------------------------------------------------------------- weights -> fragment-linear f16
// layout: [k(9)][kb][n0][lane(64)][j(8)], elem = W[co=n0*16+(l&15)][c=kb*32+(l>>4)*8+j][k]
__global__ __launch_bounds__(256) void k_prep(
    const float* __restrict__ cw1, const float* __restrict__ ow1, const float* __restrict__ mw1,
    const float* __restrict__ cw2, const float* __restrict__ ow2, const float* __restrict__ mw2,
    us* __restrict__ d1, us* __restrict__ d2, us* __restrict__ a1, us* __restrict__ a2){
  const int e = blockIdx.x*TPB + threadIdx.x;
  if (e < 73728){  // deform1: KB=2, NT=8, per-k 8192
    int k = e/8192, r = e%8192, kb = r/4096, r2 = r%4096;
    int n0 = r2>>9, q = r2&511, l = q>>3, j = q&7;
    int co = n0*16 + (l&15), c = kb*32 + (l>>4)*8 + j;
    d1[e] = f2h(cw1[(co*64 + c)*9 + k]);
  }
  if (e < 147456){ // deform2: KB=4, NT=8, per-k 16384
    int k = e/16384, r = e%16384, kb = r/4096, r2 = r%4096;
    int n0 = r2>>9, q = r2&511, l = q>>3, j = q&7;
    int co = n0*16 + (l&15), c = kb*32 + (l>>4)*8 + j;
    d2[e] = f2h(cw2[(co*128 + c)*9 + k]);
  }
  if (e < 18432){  // aux1: KB=2, NT=2, per-k 2048
    int k = e/2048, r = e%2048, kb = r/1024, r2 = r%1024;
    int n0 = r2>>9, q = r2&511, l = q>>3, j = q&7;
    int co = n0*16 + (l&15), c = kb*32 + (l>>4)*8 + j;
    float w = (co < 18) ? ow1[(co*64 + c)*9 + k] : (co < 27 ? mw1[((co-18)*64 + c)*9 + k] : 0.f);
    a1[e] = f2h(w);
  }
  if (e < 36864){  // aux2: KB=4, NT=2, per-k 4096
    int k = e/4096, r = e%4096, kb = r/1024, r2 = r%1024;
    int n0 = r2>>9, q = r2&511, l = q>>3, j = q&7;
    int co = n0*16 + (l&15), c = kb*32 + (l>>4)*8 + j;
    float w = (co < 18) ? ow2[(co*128 + c)*9 + k] : (co < 27 ? mw2[((co-18)*128 + c)*9 + k] : 0.f);
    a2[e] = f2h(w);
  }
}

// ---------------------------------------------------------------- fused aux + deformable conv (f16)
// One block = one (b,ho). Phase A: aux 3x3 conv, rows staged (copy, f16) -> 27 aux ch.
// Tables: corners + f16x2-packed mask-folded bilinear weights. Phase B: per-(tap,32ch)
// chunks double-buffered; gather = 4x uint4 corner loads + v_perm pairing + fdot2 blend.
// XOR-swizzled LDS quads (<=2-way conflicts). Waves partition N (2 of 8 co-tiles each).
template<int CIN, int STAGE>
__global__ __launch_bounds__(256, 4) void k_fused(
    const us* __restrict__ inT,
    const us* __restrict__ wb_aux, const us* __restrict__ wb_def,
    const float* __restrict__ bn_g, const float* __restrict__ bn_b,
    const float* __restrict__ bn_m, const float* __restrict__ bn_v,
    us* __restrict__ outT, float* __restrict__ partial){
  constexpr int KB   = CIN/32;
  constexpr int NC   = 9*KB;
  constexpr int WE_A = 2*KB*512;
  constexpr int WE_D = 8*KB*512;

  __shared__ __align__(16) us pool[6336];   // rows 198*32 | am f32[27*66] | g 2*2048
  __shared__ uint2 otab[576];
  __shared__ uint2 wtab[576];               // f16x2 (w00,w01),(w10,w11)
  __shared__ float extra[256];

  const int id  = blockIdx.x;
  const int nid = (id & 7)*128 + (id >> 3); // XCD swizzle (1024 % 8 == 0, bijective)
  const int b = nid >> 6, ho = nid & 63;
  const int tid = threadIdx.x;
  const us* __restrict__ inb = inT + (size_t)b*4096*CIN;

  if (STAGE == 1 && tid < 128){
    float inv = rsqrtf(bn_v[tid] + 1e-5f)*bn_g[tid];
    extra[tid] = inv; extra[128 + tid] = bn_b[tid] - bn_m[tid]*inv;
  }

  const int lane = tid & 63, lr = lane & 15, lg = lane >> 4;
  const int wv = tid >> 6;

  // ===== phase A: aux conv, rows staged (pure f16 copy) =====
  f32x4 aacc[2];
  aacc[0] = (f32x4){0.f,0.f,0.f,0.f}; aacc[1] = (f32x4){0.f,0.f,0.f,0.f};
  for (int kb = 0; kb < KB; ++kb){
    if (kb) __syncthreads();
    for (int s = tid; s < 792; s += 256){   // 3*66 slots x 4 ch-quads
      const int slot = s >> 2, cq = s & 3;
      const int r = slot/66, p = slot - r*66;
      const int y = ho - 1 + r, x = p - 1;
      uint4 q = make_uint4(0u,0u,0u,0u);
      if (y >= 0 && y < 64 && x >= 0 && x < 64)
        q = *(const uint4*)(inb + (size_t)(y*64 + x)*CIN + kb*32 + cq*8);
      *(uint4*)(pool + slot*32 + swz(slot, cq)*8) = q;
    }
    __syncthreads();
    #pragma unroll
    for (int k = 0; k < 9; ++k){
      const int kh = k/3, kw = k - kh*3;
      const int slot = kh*66 + wv*16 + lr + kw;
      f16x8 a = *(const f16x8*)(pool + slot*32 + swz(slot, lg)*8);
      #pragma unroll
      for (int n = 0; n < 2; ++n){
        f16x8 bf = *(const f16x8*)(wb_aux + (size_t)k*WE_A + (size_t)(kb*2 + n)*512 + lane*8);
        aacc[n] = MFMA16(a, bf, aacc[n]);
      }
    }
  }
  __syncthreads();                           // rows dead; am may alias

  float* am = (float*)pool;                  // [27][66]
  #pragma unroll
  for (int n = 0; n < 2; ++n){
    const int co = n*16 + lr;
    if (co < 27){
      #pragma unroll
      for (int i = 0; i < 4; ++i) am[co*66 + wv*16 + lg*4 + i] = aacc[n][i];
    }
  }
  __syncthreads();

  // ===== bilinear tables =====
  for (int it = 0; it < 3; ++it){
    const int sid = it*256 + tid;
    if (sid < 576){
      const int k = sid >> 6, px = sid & 63;
      const int kh = k/3, kw = k - kh*3;
      float oy = am[(2*k)*66 + px];
      float ox = am[(2*k+1)*66 + px];
      float mv = 1.f/(1.f + expf(-am[(18+k)*66 + px]));
      float py  = (float)(ho - 1 + kh) + oy;
      float pxx = (float)(px - 1 + kw) + ox;
      float fyf = floorf(py), fxf = floorf(pxx);
      int y0 = (int)fyf, x0 = (int)fxf;
      float dy = py - fyf, dx = pxx - fxf;
      bool vy0 = (y0 >= 0) && (y0 < 64), vy1 = (y0 >= -1) && (y0 < 63);
      bool vx0 = (x0 >= 0) && (x0 < 64), vx1 = (x0 >= -1) && (x0 < 63);
      int y0c = min(max(y0,0),63), y1c = min(max(y0+1,0),63);
      int x0c = min(max(x0,0),63), x1c = min(max(x0+1,0),63);
      otab[sid] = make_uint2((unsigned)(y0c*64 + x0c) | ((unsigned)(y0c*64 + x1c) << 16),
                             (unsigned)(y1c*64 + x0c) | ((unsigned)(y1c*64 + x1c) << 16));
      float w00 = (1.f-dy)*(1.f-dx)*mv*((vy0 && vx0) ? 1.f : 0.f);
      float w01 = (1.f-dy)*dx     *mv*((vy0 && vx1) ? 1.f : 0.f);
      float w10 = dy*(1.f-dx)     *mv*((vy1 && vx0) ? 1.f : 0.f);
      float w11 = dy*dx           *mv*((vy1 && vx1) ? 1.f : 0.f);
      wtab[sid] = make_uint2((unsigned)f2h(w00) | ((unsigned)f2h(w01) << 16),
                             (unsigned)f2h(w10) | ((unsigned)f2h(w11) << 16));
    }
  }
  __syncthreads();                           // am dead; g buffers may alias

  // ===== phase B: deform conv, double-buffered chunks =====
  f32x4 acc[4][2];
  #pragma unroll
  for (int m = 0; m < 4; ++m){ acc[m][0] = (f32x4){0.f,0.f,0.f,0.f}; acc[m][1] = (f32x4){0.f,0.f,0.f,0.f}; }

  auto stage_def = [&](int i, us* dst){
    const int k = i/KB, kb = i - (i/KB)*KB;
    const int px = tid >> 2, cq = tid & 3;
    const uint2 o = otab[k*64 + px];
    const uint2 wp = wtab[k*64 + px];
    const f16x2 wAB = u2h2(wp.x), wCD = u2h2(wp.y);
    const int c0 = kb*32 + cq*8;
    const uint4 A = *(const uint4*)(inb + (size_t)(o.x & 0xffffu)*CIN + c0);
    const uint4 B = *(const uint4*)(inb + (size_t)(o.x >> 16)    *CIN + c0);
    const uint4 C = *(const uint4*)(inb + (size_t)(o.y & 0xffffu)*CIN + c0);
    const uint4 D = *(const uint4*)(inb + (size_t)(o.y >> 16)    *CIN + c0);
    const unsigned* Au = (const unsigned*)&A;
    const unsigned* Bu = (const unsigned*)&B;
    const unsigned* Cu = (const unsigned*)&C;
    const unsigned* Du = (const unsigned*)&D;
    uint4 r;
    unsigned* ru = (unsigned*)&r;
    #pragma unroll
    for (int jj = 0; jj < 4; ++jj){
      float vL = __builtin_amdgcn_fdot2(wAB, u2h2(__builtin_amdgcn_perm(Au[jj], Bu[jj], PERM_LO)), 0.f, false);
      vL = __builtin_amdgcn_fdot2(wCD, u2h2(__builtin_amdgcn_perm(Cu[jj], Du[jj], PERM_LO)), vL, false);
      float vH = __builtin_amdgcn_fdot2(wAB, u2h2(__builtin_amdgcn_perm(Au[jj], Bu[jj], PERM_HI)), 0.f, false);
      vH = __builtin_amdgcn_fdot2(wCD, u2h2(__builtin_amdgcn_perm(Cu[jj], Du[jj], PERM_HI)), vH, false);
      ru[jj] = (unsigned)f2h(vL) | ((unsigned)f2h(vH) << 16);
    }
    *(uint4*)(dst + px*32 + swz(px, cq)*8) = r;
  };
  auto mfma_def = [&](int i, const us* src){
    const int k = i/KB, kb = i - (i/KB)*KB;
    f16x8 a[4];
    #pragma unroll
    for (int mt = 0; mt < 4; ++mt){
      const int row = mt*16 + lr;
      a[mt] = *(const f16x8*)(src + row*32 + swz(row, lg)*8);
    }
    #pragma unroll
    for (int nt = 0; nt < 2; ++nt){
      f16x8 bf = *(const f16x8*)(wb_def + (size_t)k*WE_D + (size_t)(kb*8 + wv*2 + nt)*512 + lane*8);
      #pragma unroll
      for (int mt = 0; mt < 4; ++mt)
        acc[mt][nt] = MFMA16(a[mt], bf, acc[mt][nt]);
    }
  };

  us* g0 = pool;
  us* g1 = pool + 2048;
  stage_def(0, g0);
  __syncthreads();
  for (int i = 0; i < NC; ++i){
    us* cur = (i & 1) ? g1 : g0;
    us* nxt = (i & 1) ? g0 : g1;
    if (i + 1 < NC) stage_def(i+1, nxt);
    mfma_def(i, cur);
    __syncthreads();
  }

  // ===== epilogue =====
  if (STAGE == 1){
    const size_t rowbase = (size_t)(b*4096 + ho*64)*128;
    #pragma unroll
    for (int mt = 0; mt < 4; ++mt){
      const int pxl = mt*16 + lg*4;
      #pragma unroll
      for (int nt = 0; nt < 2; ++nt){
        const int co = (wv*2 + nt)*16 + lr;
        const float inv = extra[co], bia = extra[128 + co];
        #pragma unroll
        for (int i = 0; i < 4; ++i){
          float v = acc[mt][nt][i]*inv + bia;
          outT[rowbase + (size_t)(pxl + i)*128 + co] = f2h(fmaxf(v, 0.f));
        }
      }
    }
  } else {
    #pragma unroll
    for (int nt = 0; nt < 2; ++nt){
      float s = 0.f;
      #pragma unroll
      for (int mt = 0; mt < 4; ++mt)
        s += acc[mt][nt][0] + acc[mt][nt][1] + acc[mt][nt][2] + acc[mt][nt][3];
      s += __shfl_xor(s, 16);
      s += __shfl_xor(s, 32);
      if (lane < 16) extra[(wv*2 + nt)*16 + lane] = s;
    }
    __syncthreads();
    if (tid < 128) partial[(size_t)(b*64 + ho)*128 + tid] = extra[tid];
  }
}

// ---------------------------------------------------------------- pool + BN2 fold
__global__ __launch_bounds__(256) void k_pool(
    const float* __restrict__ partial,
    const float* __restrict__ g2, const float* __restrict__ b2,
    const float* __restrict__ m2, const float* __restrict__ v2,
    float* __restrict__ pooled){
  const int t = blockIdx.x*TPB + threadIdx.x;
  if (t >= 2048) return;
  const int b = t >> 7, c = t & 127;
  float s = 0.f;
  for (int h = 0; h < 64; ++h) s += partial[(b*64 + h)*128 + c];
  const float inv = rsqrtf(v2[c] + 1e-5f)*g2[c];
  pooled[t] = s*(1.f/4096.f)*inv + (b2[c] - m2[c]*inv);
}

// ---------------------------------------------------------------- fc
__global__ __launch_bounds__(256) void k_fc(
    const float* __restrict__ pooled, const float* __restrict__ fcw,
    const float* __restrict__ fcb, float* __restrict__ outp){
  const int t = blockIdx.x*TPB + threadIdx.x;
  if (t >= 16000) return;
  const int b = t/1000, n = t - b*1000;
  const float* p = pooled + b*128;
  const float* w = fcw + n*128;
  float s = fcb[n];
  #pragma unroll
  for (int c = 0; c < 128; c += 4){
    const float4 pv = *(const float4*)(p + c);
    const float4 wv = *(const float4*)(w + c);
    s = fmaf(pv.x, wv.x, s); s = fmaf(pv.y, wv.y, s);
    s = fmaf(pv.z, wv.z, s); s = fmaf(pv.w, wv.w, s);
  }
  outp[t] = s;
}

extern "C" void kernel_launch(void* const* d_in, const int* in_sizes, int n_in,
                              void* d_out, int out_size, void* d_ws, size_t ws_size,
                              hipStream_t stream){
  const float* x      = (const float*)d_in[0];
  const float* conv1w = (const float*)d_in[1];
  const float* off1w  = (const float*)d_in[2];
  const float* mod1w  = (const float*)d_in[3];
  const float* bn1g   = (const float*)d_in[4];
  const float* bn1b   = (const float*)d_in[5];
  const float* bn1m   = (const float*)d_in[6];
  const float* bn1v   = (const float*)d_in[7];
  const float* conv2w = (const float*)d_in[8];
  const float* off2w  = (const float*)d_in[9];
  const float* mod2w  = (const float*)d_in[10];
  const float* bn2g   = (const float*)d_in[11];
  const float* bn2b   = (const float*)d_in[12];
  const float* bn2m   = (const float*)d_in[13];
  const float* bn2v   = (const float*)d_in[14];
  const float* fcw    = (const float*)d_in[15];
  const float* fcb    = (const float*)d_in[16];

  char* w = (char*)d_ws;
  us*    xT      = (us*)(w);                      //  8,388,608 B
  us*    out1T   = (us*)(w + 8388608);            // 16,777,216 B
  float* partial = (float*)(w + 25165824);        //    524,288 B
  float* pooled  = (float*)(w + 25690112);        //      8,192 B
  us*    wb_d1   = (us*)(w + 25698304);           //    147,456 B
  us*    wb_d2   = (us*)(w + 25845760);           //    294,912 B
  us*    wb_a1   = (us*)(w + 26140672);           //     36,864 B
  us*    wb_a2   = (us*)(w + 26177536);           //     73,728 B

  k_transpose_x<<<dim3(64,16), TPB, 0, stream>>>(x, xT);
  k_prep<<<576, TPB, 0, stream>>>(conv1w, off1w, mod1w, conv2w, off2w, mod2w,
                                  wb_d1, wb_d2, wb_a1, wb_a2);

  k_fused<64,1><<<1024, TPB, 0, stream>>>(
      xT, wb_a1, wb_d1, bn1g, bn1b, bn1m, bn1v, out1T, nullptr);
  k_fused<128,2><<<1024, TPB, 0, stream>>>(
      out1T, wb_a2, wb_d2, nullptr, nullptr, nullptr, nullptr, nullptr, partial);

  k_pool<<<8, TPB, 0, stream>>>(partial, bn2g, bn2b, bn2m, bn2v, pooled);
  k_fc<<<63, TPB, 0, stream>>>(pooled, fcw, fcb, (float*)d_out);
}